// Round 7
// baseline (732.461 us; speedup 1.0000x reference)
//
#include <hip/hip_runtime.h>

#define SEQ   512
#define BATCH 4
#define NN    128
#define HID   64
#define G4    256   // 4*HID gates per layer

using bf16x8 = __attribute__((ext_vector_type(8))) short;   // 8 bf16 in 4 VGPRs
using f32x4  = __attribute__((ext_vector_type(4))) float;

__device__ __forceinline__ float frcp(float x)  { return __builtin_amdgcn_rcpf(x); }
__device__ __forceinline__ float fsigm(float x) { return frcp(1.f + __expf(-x)); }
__device__ __forceinline__ float ftanh(float x) { return 1.f - 2.f * frcp(1.f + __expf(2.f * x)); }
__device__ __forceinline__ float lrelu(float x) { return x > 0.f ? x : 0.2f * x; }
__device__ __forceinline__ float dot4f(float4 w, float4 h) {
  return fmaf(w.x, h.x, fmaf(w.y, h.y, fmaf(w.z, h.z, w.w * h.w)));
}
// float -> bf16 bits, round-to-nearest-even
__device__ __forceinline__ short f2bf(float f) {
  unsigned u = __float_as_uint(f);
  return (short)((u + 0x7FFFu + ((u >> 16) & 1u)) >> 16);
}
__device__ __forceinline__ float bf2f(short s) {
  return __uint_as_float(((unsigned)(unsigned short)s) << 16);
}

// ---------------------------------------------------------------------------
// prep_kernel (verified R4-R6): blocks [0,128) X0 GEMM (transposed store:
// (t,b,unit) -> 4 contiguous gate values i,f,g,o); blocks [128,132) GAT.
// ---------------------------------------------------------------------------
__global__ __launch_bounds__(512) void prep_kernel(
    const float* __restrict__ x, const float* __restrict__ Wih0,
    const float* __restrict__ bih0, const float* __restrict__ bhh0,
    float* __restrict__ X0,
    const int* __restrict__ adj, const float* __restrict__ emb_w,
    const float* __restrict__ emb_b,
    const float* __restrict__ W1, const float* __restrict__ a1,
    const float* __restrict__ W2, const float* __restrict__ a2,
    float* __restrict__ xg_out)
{
  const int tid = threadIdx.x;
  if (blockIdx.x < 128) {
    __shared__ __align__(16) float xls[NN];
    const int g = tid >> 1, half = tid & 1;
    float4 w4[16];
    {
      const float4* wp = reinterpret_cast<const float4*>(Wih0 + g * NN + half * 64);
#pragma unroll
      for (int i = 0; i < 16; ++i) w4[i] = wp[i];
    }
    const float bsum = bih0[g] + bhh0[g];
    const int r0 = blockIdx.x * 16;
    for (int r = r0; r < r0 + 16; ++r) {
      const int tt = r >> 2, b = r & 3;
      if (tid < NN) xls[tid] = x[(b * SEQ + tt) * NN + tid];
      __syncthreads();
      const float4* hp = reinterpret_cast<const float4*>(&xls[half * 64]);
      float p0 = 0.f, p1 = 0.f, p2 = 0.f, p3 = 0.f;
#pragma unroll
      for (int k = 0; k < 16; k += 4) {
        p0 += dot4f(w4[k],     hp[k]);
        p1 += dot4f(w4[k + 1], hp[k + 1]);
        p2 += dot4f(w4[k + 2], hp[k + 2]);
        p3 += dot4f(w4[k + 3], hp[k + 3]);
      }
      float p = (p0 + p1) + (p2 + p3);
      p += __shfl_xor(p, 1);
      if (half == 0) X0[r * G4 + (g & 63) * 4 + (g >> 6)] = p + bsum;
      __syncthreads();
    }
    return;
  }
  const int b = blockIdx.x - 128;
  __shared__ float adjm[NN * 129];
  __shared__ __align__(16) float xls[NN];
  __shared__ float u[16], v[16];
  __shared__ float Wh2[NN][9];
  __shared__ float f1b[NN], f2b[NN];
  __shared__ float p[NN];

  for (int idx = tid; idx < NN * NN; idx += 512)
    adjm[(idx >> 7) * 129 + (idx & 127)] = (adj[idx] > 0) ? 1.f : 0.f;
  if (tid < NN) xls[tid] = x[(b * SEQ + (SEQ - 1)) * NN + tid];
  if (tid < 16) {
    float uu = 0.f, vv = 0.f;
    for (int fp = 0; fp < 16; ++fp) {
      uu += emb_w[fp] * W1[fp * 16 + tid];
      vv += emb_b[fp] * W1[fp * 16 + tid];
    }
    u[tid] = uu; v[tid] = vv;
  }
  __syncthreads();
  float s1 = 0.f, t1 = 0.f, s2 = 0.f, t2 = 0.f;
  for (int f = 0; f < 16; ++f) {
    s1 += u[f] * a1[f];      t1 += v[f] * a1[f];
    s2 += u[f] * a1[16 + f]; t2 += v[f] * a1[16 + f];
  }
  if (tid < NN) {
    const int i = tid;
    const float f1i = xls[i] * s1 + t1;
    float m = -1e30f;
    for (int j = 0; j < NN; ++j)
      if (adjm[i * 129 + j] != 0.f)
        m = fmaxf(m, lrelu(f1i + xls[j] * s2 + t2));
    float ssum = 0.f, ps = 0.f;
    for (int j = 0; j < NN; ++j)
      if (adjm[i * 129 + j] != 0.f) {
        const float wgt = __expf(lrelu(f1i + xls[j] * s2 + t2) - m);
        ssum += wgt; ps += wgt * xls[j];
      }
    p[i] = ps / ssum;
  }
  __syncthreads();
  if (tid < NN) {
    const int i = tid;
    float xg1[16];
#pragma unroll
    for (int f = 0; f < 16; ++f) {
      const float ov = p[i] * u[f] + v[f];
      xg1[f] = ov > 0.f ? ov : expm1f(ov);
    }
    float wrow[8];
#pragma unroll
    for (int f2 = 0; f2 < 8; ++f2) wrow[f2] = 0.f;
#pragma unroll
    for (int f = 0; f < 16; ++f) {
      const float xv = xg1[f];
#pragma unroll
      for (int f2 = 0; f2 < 8; ++f2) wrow[f2] += xv * W2[f * 8 + f2];
    }
    float fb1 = 0.f, fb2 = 0.f;
#pragma unroll
    for (int f2 = 0; f2 < 8; ++f2) {
      Wh2[i][f2] = wrow[f2];
      fb1 += wrow[f2] * a2[f2];
      fb2 += wrow[f2] * a2[8 + f2];
    }
    f1b[i] = fb1; f2b[i] = fb2;
  }
  __syncthreads();
  if (tid < NN) {
    const int i = tid;
    const float fi = f1b[i];
    float m = -1e30f;
    for (int j = 0; j < NN; ++j)
      if (adjm[i * 129 + j] != 0.f)
        m = fmaxf(m, lrelu(fi + f2b[j]));
    float ssum = 0.f;
    float o[8];
#pragma unroll
    for (int f2 = 0; f2 < 8; ++f2) o[f2] = 0.f;
    for (int j = 0; j < NN; ++j)
      if (adjm[i * 129 + j] != 0.f) {
        const float wgt = __expf(lrelu(fi + f2b[j]) - m);
        ssum += wgt;
#pragma unroll
        for (int f2 = 0; f2 < 8; ++f2) o[f2] += wgt * Wh2[j][f2];
      }
    const float inv = 1.f / ssum;
#pragma unroll
    for (int f2 = 0; f2 < 8; ++f2)
      xg_out[b * (NN * 8) + i * 8 + f2] = o[f2] * inv;
  }
}

// ---------------------------------------------------------------------------
// lstm_heads: MFMA 2-layer LSTM scan, ALL 4 batches in ONE block (512 thr,
// 8 waves, 2/SIMD). Split-bf16 precision: w = w_hi + w_lo; B-operand packs
// h_hi in cols 0-3 and h_lo in cols 4-7 -> D accumulates (w_hi+w_lo)*h_hi in
// cols 0-3 and *h_lo in cols 4-7; fold with one shfl_xor(4).
// Row permutation W'[4u+g] = W[g*64+u] puts a unit's i,f,g,o gates into one
// lane's 4 C-regs (C/D layout: col=lane&15, row=quad*4+reg — HW-verified).
// A-operand layout: A[m=lane&15][k=quad*8+j]. A-frags live in AGPRs, which
// MFMA reads natively — no v_accvgpr_read tax (R6's 30% VALU overhead).
// Phase B redistributes (unit,layer,batch)->thread 1:1: acts at full lane
// efficiency. L1 skewed one step (iter i: h0[i], h1[i-1]). 513 iters,
// 2 barriers each. Fused heads for all 4 batches at the end.
// ---------------------------------------------------------------------------
#define HSTRIDE 136   // bf16 row stride in hfs (272B: 2-way bank aliasing = free)
#define GSTRIDE 260   // f32 stride per (b,l) in gact

__global__ __attribute__((amdgpu_flat_work_group_size(512, 512),
                          amdgpu_waves_per_eu(2, 2)))
void lstm_heads(
    const float* __restrict__ X0T, const float* __restrict__ Whh0,
    const float* __restrict__ Wih1, const float* __restrict__ Whh1,
    const float* __restrict__ bih1, const float* __restrict__ bhh1,
    const float* __restrict__ xg,
    const float* __restrict__ dw1, const float* __restrict__ db1,
    const float* __restrict__ dw2, const float* __restrict__ db2,
    const float* __restrict__ rw1, const float* __restrict__ rb1,
    const float* __restrict__ rw2, const float* __restrict__ rb2,
    const float* __restrict__ vw1, const float* __restrict__ vb1,
    const float* __restrict__ vw2, const float* __restrict__ vb2,
    float* __restrict__ out)
{
  const int t    = threadIdx.x;
  const int lane = t & 63;
  const int wv   = t >> 6;        // wave 0..7
  const int q    = lane >> 4;     // quad 0..3
  const int col  = lane & 15;     // MFMA n-col (batch 0-3 = h_hi, 4-7 = h_lo)

  __shared__ __align__(16) short hfs[2][16 * HSTRIDE];  // B operand, bf16
  __shared__ __align__(16) float gact[8 * GSTRIDE];     // raw gates [(b*2+l)][u*4+g]
  __shared__ __align__(16) float xl[BATCH * HID];
  __shared__ float cbuf[BATCH * 1088];
  __shared__ float hidc[12 * 32];

  // ---- A-fragment init: pre-permuted, split into bf16 hi/lo ----
  bf16x8 a0h[2][2], a0l[2][2];    // [tile][kchunk], L0 (Whh0, K=64)
  bf16x8 a1h[2][4], a1l[2][4];    // L1 ([Wih1|Whh1], K=128)
#pragma unroll
  for (int ti = 0; ti < 2; ++ti) {
    const int T = 2 * wv + ti;          // M-tile 0..15
    const int m = 16 * T + col;         // permuted row
    const int uu = m >> 2, g = m & 3;
    const int row = g * 64 + uu;        // original gate-row
#pragma unroll
    for (int c = 0; c < 2; ++c) {
      const float* src = Whh0 + row * 64 + 32 * c + 8 * q;
#pragma unroll
      for (int j = 0; j < 8; ++j) {
        const float f = src[j];
        const short hi = f2bf(f);
        a0h[ti][c][j] = hi;
        a0l[ti][c][j] = f2bf(f - bf2f(hi));
      }
    }
#pragma unroll
    for (int c = 0; c < 4; ++c) {
      const int k0 = 32 * c + 8 * q;
      const float* src = (k0 < 64) ? (Wih1 + row * 64 + k0)
                                   : (Whh1 + row * 64 + (k0 - 64));
#pragma unroll
      for (int j = 0; j < 8; ++j) {
        const float f = src[j];
        const short hi = f2bf(f);
        a1h[ti][c][j] = hi;
        a1l[ti][c][j] = f2bf(f - bf2f(hi));
      }
    }
  }

  // ---- phase-B identity & per-thread state ----
  const int u2 = t & 63;          // unit
  const int l2 = (t >> 6) & 1;    // layer
  const int b2 = t >> 7;          // batch
  f32x4 b1s = {0.f, 0.f, 0.f, 0.f};
  if (l2 == 1) {
    b1s[0] = bih1[u2]       + bhh1[u2];
    b1s[1] = bih1[64 + u2]  + bhh1[64 + u2];
    b1s[2] = bih1[128 + u2] + bhh1[128 + u2];
    b1s[3] = bih1[192 + u2] + bhh1[192 + u2];
  }
  float cst = 0.f;
  f32x4 cur = {0.f, 0.f, 0.f, 0.f};
  if (l2 == 0) cur = *reinterpret_cast<const f32x4*>(X0T + (0 * 4 + b2) * G4 + u2 * 4);

  // zero both hfrag buffers (h0[-1]=h1[-2]=0; rows 8-15 stay 0 forever)
  for (int k = t; k < 2 * 16 * HSTRIDE; k += 512)
    (&hfs[0][0])[k] = 0;
  __syncthreads();

  // =================== scan: 513 iterations ===================
  for (int i = 0; i <= SEQ; ++i) {
    // ---- Phase A: MFMA gates into gact ----
    {
      const short* bp = &hfs[i & 1][0] + col * HSTRIDE + 8 * q;
      const bf16x8 B0 = *reinterpret_cast<const bf16x8*>(bp);
      const bf16x8 B1 = *reinterpret_cast<const bf16x8*>(bp + 32);
      const bf16x8 B2 = *reinterpret_cast<const bf16x8*>(bp + 64);
      const bf16x8 B3 = *reinterpret_cast<const bf16x8*>(bp + 96);
#pragma unroll
      for (int ti = 0; ti < 2; ++ti) {
        const int u_ = 4 * (2 * wv + ti) + q;
        // L0: K=64 over h0[i-1]
        f32x4 D = {0.f, 0.f, 0.f, 0.f};
        D = __builtin_amdgcn_mfma_f32_16x16x32_bf16(a0l[ti][0], B0, D, 0, 0, 0);
        D = __builtin_amdgcn_mfma_f32_16x16x32_bf16(a0l[ti][1], B1, D, 0, 0, 0);
        D = __builtin_amdgcn_mfma_f32_16x16x32_bf16(a0h[ti][0], B0, D, 0, 0, 0);
        D = __builtin_amdgcn_mfma_f32_16x16x32_bf16(a0h[ti][1], B1, D, 0, 0, 0);
        f32x4 Gv;
#pragma unroll
        for (int r = 0; r < 4; ++r) {
          const float d = D[r];
          Gv[r] = d + __shfl_xor(d, 4);
        }
        if (col < 4)
          *reinterpret_cast<f32x4*>(&gact[(col * 2 + 0) * GSTRIDE + u_ * 4]) = Gv;
        // L1: K=128 over [h0[i-1] ; h1[i-2]]
        f32x4 E = {0.f, 0.f, 0.f, 0.f};
        E = __builtin_amdgcn_mfma_f32_16x16x32_bf16(a1l[ti][0], B0, E, 0, 0, 0);
        E = __builtin_amdgcn_mfma_f32_16x16x32_bf16(a1l[ti][1], B1, E, 0, 0, 0);
        E = __builtin_amdgcn_mfma_f32_16x16x32_bf16(a1l[ti][2], B2, E, 0, 0, 0);
        E = __builtin_amdgcn_mfma_f32_16x16x32_bf16(a1l[ti][3], B3, E, 0, 0, 0);
        E = __builtin_amdgcn_mfma_f32_16x16x32_bf16(a1h[ti][0], B0, E, 0, 0, 0);
        E = __builtin_amdgcn_mfma_f32_16x16x32_bf16(a1h[ti][1], B1, E, 0, 0, 0);
        E = __builtin_amdgcn_mfma_f32_16x16x32_bf16(a1h[ti][2], B2, E, 0, 0, 0);
        E = __builtin_amdgcn_mfma_f32_16x16x32_bf16(a1h[ti][3], B3, E, 0, 0, 0);
        f32x4 Gw;
#pragma unroll
        for (int r = 0; r < 4; ++r) {
          const float d = E[r];
          Gw[r] = d + __shfl_xor(d, 4);
        }
        if (col < 4)
          *reinterpret_cast<f32x4*>(&gact[(col * 2 + 1) * GSTRIDE + u_ * 4]) = Gw;
      }
    }
    __syncthreads();

    // ---- Phase B: acts + cell update, 1 (unit,layer,batch) per thread ----
    {
      const f32x4 gv = *reinterpret_cast<const f32x4*>(
          &gact[(b2 * 2 + l2) * GSTRIDE + u2 * 4]);
      f32x4 nxt = cur;
      if (l2 == 0) {
        const int it = (i + 1 < SEQ) ? (i + 1) : (SEQ - 1);
        nxt = *reinterpret_cast<const f32x4*>(X0T + (it * 4 + b2) * G4 + u2 * 4);
      }
      const f32x4 pre = (l2 == 0) ? (gv + cur) : (gv + b1s);
      const bool act = (l2 == 0) ? (i < SEQ) : (i >= 1);
      if (act) {
        const float gi = fsigm(pre[0]);
        const float gf = fsigm(pre[1]);
        const float gg = ftanh(pre[2]);
        const float go = fsigm(pre[3]);
        cst = fmaf(gf, cst, gi * gg);
        const float h = go * ftanh(cst);
        const short hi = f2bf(h);
        const short lo = f2bf(h - bf2f(hi));
        const int wb = (i + 1) & 1;
        const int kk = l2 * 64 + u2;
        hfs[wb][b2 * HSTRIDE + kk] = hi;
        hfs[wb][(b2 + 4) * HSTRIDE + kk] = lo;
        if (l2 == 1 && i == SEQ) xl[b2 * HID + u2] = h;
      }
      cur = nxt;
    }
    __syncthreads();
  }

  // =================== fused heads, all 4 batches ===================
  for (int bb = 0; bb < BATCH; ++bb)
    for (int k = t; k < 1088; k += 512)
      cbuf[bb * 1088 + k] = (k < 64) ? xl[bb * HID + k] : xg[bb * 1024 + (k - 64)];
  __syncthreads();
  if (t < 384) {
    const int bh = t >> 5, h = t & 31;
    const int head = bh % 3, bI = bh / 3;
    const float* w1 = (head == 0) ? dw1 : (head == 1) ? rw1 : vw1;
    const float* b1 = (head == 0) ? db1 : (head == 1) ? rb1 : vb1;
    const float* c = &cbuf[bI * 1088];
    float a0 = 0.f, a1v = 0.f, a2v = 0.f, a3v = 0.f;
    for (int k = 0; k < 1088; k += 4) {
      a0  = fmaf(c[k],     w1[k * 32 + h],       a0);
      a1v = fmaf(c[k + 1], w1[(k + 1) * 32 + h], a1v);
      a2v = fmaf(c[k + 2], w1[(k + 2) * 32 + h], a2v);
      a3v = fmaf(c[k + 3], w1[(k + 3) * 32 + h], a3v);
    }
    hidc[(bI * 3 + head) * 32 + h] = fmaxf(b1[h] + ((a0 + a1v) + (a2v + a3v)), 0.f);
  }
  __syncthreads();
  if (t < 16) {
    int head2, bo, o, odim;
    if (t < 4)      { head2 = 0; bo = t;            o = 0;             odim = 1; }
    else if (t < 8) { head2 = 1; bo = t - 4;        o = 0;             odim = 1; }
    else            { head2 = 2; bo = (t - 8) >> 1; o = (t - 8) & 1;   odim = 2; }
    const float* w2  = (head2 == 0) ? dw2 : (head2 == 1) ? rw2 : vw2;
    const float* b2p = (head2 == 0) ? db2 : (head2 == 1) ? rb2 : vb2;
    float acc = b2p[o];
    for (int hh = 0; hh < 32; ++hh)
      acc = fmaf(hidc[(bo * 3 + head2) * 32 + hh], w2[hh * odim + o], acc);
    const int off = (t < 4) ? bo : (t < 8) ? (4 + bo) : (8 + 2 * bo + o);
    out[off] = acc;   // [dir(4) | ret(4) | vol(4x2)] flat
  }
}

// ---------------------------------------------------------------------------
extern "C" void kernel_launch(void* const* d_in, const int* in_sizes, int n_in,
                              void* d_out, int out_size, void* d_ws, size_t ws_size,
                              hipStream_t stream) {
  const float* x     = (const float*)d_in[0];
  const int*   adj   = (const int*)  d_in[1];
  const float* emb_w = (const float*)d_in[2];
  const float* emb_b = (const float*)d_in[3];
  const float* g1W   = (const float*)d_in[4];
  const float* g1a   = (const float*)d_in[5];
  const float* g2W   = (const float*)d_in[6];
  const float* g2a   = (const float*)d_in[7];
  const float* Wih0  = (const float*)d_in[8];
  const float* Whh0  = (const float*)d_in[9];
  const float* bih0  = (const float*)d_in[10];
  const float* bhh0  = (const float*)d_in[11];
  const float* Wih1  = (const float*)d_in[12];
  const float* Whh1  = (const float*)d_in[13];
  const float* bih1  = (const float*)d_in[14];
  const float* bhh1  = (const float*)d_in[15];
  const float* dw1 = (const float*)d_in[16]; const float* db1 = (const float*)d_in[17];
  const float* dw2 = (const float*)d_in[18]; const float* db2 = (const float*)d_in[19];
  const float* rw1 = (const float*)d_in[20]; const float* rb1 = (const float*)d_in[21];
  const float* rw2 = (const float*)d_in[22]; const float* rb2 = (const float*)d_in[23];
  const float* vw1 = (const float*)d_in[24]; const float* vb1 = (const float*)d_in[25];
  const float* vw2 = (const float*)d_in[26]; const float* vb2 = (const float*)d_in[27];

  float* ws = (float*)d_ws;
  float* X0 = ws;                         // SEQ*BATCH*256 floats = 2 MB (transposed)
  float* xg = ws + SEQ * BATCH * G4;      // 4096 floats
  float* out = (float*)d_out;

  hipLaunchKernelGGL(prep_kernel, dim3(132), dim3(512), 0, stream,
                     x, Wih0, bih0, bhh0, X0,
                     adj, emb_w, emb_b, g1W, g1a, g2W, g2a, xg);
  hipLaunchKernelGGL(lstm_heads, dim3(1), dim3(512), 0, stream,
                     X0, Whh0, Wih1, Whh1, bih1, bhh1, xg,
                     dw1, db1, dw2, db2, rw1, rb1, rw2, rb2,
                     vw1, vb1, vw2, vb2, out);
}

// Round 8
// 593.360 us; speedup vs baseline: 1.2344x; 1.2344x over previous
//
#include <hip/hip_runtime.h>

#define SEQ   512
#define BATCH 4
#define NN    128
#define HID   64
#define G4    256   // 4*HID gates per layer

// Fast activations: v_exp_f32 + v_rcp_f32 (abs err ~1e-6, threshold is 1e-3)
__device__ __forceinline__ float frcp(float x)  { return __builtin_amdgcn_rcpf(x); }
__device__ __forceinline__ float fsigm(float x) { return frcp(1.f + __expf(-x)); }
__device__ __forceinline__ float ftanh(float x) { return 1.f - 2.f * frcp(1.f + __expf(2.f * x)); }
__device__ __forceinline__ float lrelu(float x) { return x > 0.f ? x : 0.2f * x; }
__device__ __forceinline__ float dot4f(float4 w, float4 h) {
  return fmaf(w.x, h.x, fmaf(w.y, h.y, fmaf(w.z, h.z, w.w * h.w)));
}
// Init-time pin: block load-sinking into the loop (R4/R5: in-loop pins cause
// per-iteration scratch churn; init-only pins are the safe form).
__device__ __forceinline__ void pin4(float4& v) {
  asm volatile("" : "+v"(v.x), "+v"(v.y), "+v"(v.z), "+v"(v.w));
}
// Quad butterfly sum via self-inverse quad_perm: 0xB1={1,0,3,2}, 0x4E={2,3,0,1}.
__device__ __forceinline__ float qsum(float x) {
  x += __int_as_float(__builtin_amdgcn_update_dpp(
      0, __float_as_int(x), 0xB1, 0xF, 0xF, true));
  x += __int_as_float(__builtin_amdgcn_update_dpp(
      0, __float_as_int(x), 0x4E, 0xF, 0xF, true));
  return x;
}
__device__ __forceinline__ float dotacc(const float4* w, const float4* h, float a) {
#pragma unroll
  for (int c = 0; c < 4; ++c) {
    a = fmaf(w[c].x, h[c].x, a);
    a = fmaf(w[c].y, h[c].y, a);
    a = fmaf(w[c].z, h[c].z, a);
    a = fmaf(w[c].w, h[c].w, a);
  }
  return a;
}

// ---------------------------------------------------------------------------
// prep_kernel (verified R4-R7): blocks [0,128) X0 GEMM (transposed store:
// (t,b,unit) -> 4 contiguous gate values i,f,g,o); blocks [128,132) GAT.
// ---------------------------------------------------------------------------
__global__ __launch_bounds__(512) void prep_kernel(
    const float* __restrict__ x, const float* __restrict__ Wih0,
    const float* __restrict__ bih0, const float* __restrict__ bhh0,
    float* __restrict__ X0,
    const int* __restrict__ adj, const float* __restrict__ emb_w,
    const float* __restrict__ emb_b,
    const float* __restrict__ W1, const float* __restrict__ a1,
    const float* __restrict__ W2, const float* __restrict__ a2,
    float* __restrict__ xg_out)
{
  const int tid = threadIdx.x;
  if (blockIdx.x < 128) {
    __shared__ __align__(16) float xls[NN];
    const int g = tid >> 1, half = tid & 1;
    float4 w4[16];
    {
      const float4* wp = reinterpret_cast<const float4*>(Wih0 + g * NN + half * 64);
#pragma unroll
      for (int i = 0; i < 16; ++i) w4[i] = wp[i];
    }
    const float bsum = bih0[g] + bhh0[g];
    const int r0 = blockIdx.x * 16;
    for (int r = r0; r < r0 + 16; ++r) {
      const int tt = r >> 2, b = r & 3;
      if (tid < NN) xls[tid] = x[(b * SEQ + tt) * NN + tid];
      __syncthreads();
      const float4* hp = reinterpret_cast<const float4*>(&xls[half * 64]);
      float p0 = 0.f, p1 = 0.f, p2 = 0.f, p3 = 0.f;
#pragma unroll
      for (int k = 0; k < 16; k += 4) {
        p0 += dot4f(w4[k],     hp[k]);
        p1 += dot4f(w4[k + 1], hp[k + 1]);
        p2 += dot4f(w4[k + 2], hp[k + 2]);
        p3 += dot4f(w4[k + 3], hp[k + 3]);
      }
      float p = (p0 + p1) + (p2 + p3);
      p += __shfl_xor(p, 1);
      if (half == 0) X0[r * G4 + (g & 63) * 4 + (g >> 6)] = p + bsum;
      __syncthreads();
    }
    return;
  }
  const int b = blockIdx.x - 128;
  __shared__ float adjm[NN * 129];
  __shared__ __align__(16) float xls[NN];
  __shared__ float u[16], v[16];
  __shared__ float Wh2[NN][9];
  __shared__ float f1b[NN], f2b[NN];
  __shared__ float p[NN];

  for (int idx = tid; idx < NN * NN; idx += 512)
    adjm[(idx >> 7) * 129 + (idx & 127)] = (adj[idx] > 0) ? 1.f : 0.f;
  if (tid < NN) xls[tid] = x[(b * SEQ + (SEQ - 1)) * NN + tid];
  if (tid < 16) {
    float uu = 0.f, vv = 0.f;
    for (int fp = 0; fp < 16; ++fp) {
      uu += emb_w[fp] * W1[fp * 16 + tid];
      vv += emb_b[fp] * W1[fp * 16 + tid];
    }
    u[tid] = uu; v[tid] = vv;
  }
  __syncthreads();
  float s1 = 0.f, t1 = 0.f, s2 = 0.f, t2 = 0.f;
  for (int f = 0; f < 16; ++f) {
    s1 += u[f] * a1[f];      t1 += v[f] * a1[f];
    s2 += u[f] * a1[16 + f]; t2 += v[f] * a1[16 + f];
  }
  if (tid < NN) {
    const int i = tid;
    const float f1i = xls[i] * s1 + t1;
    float m = -1e30f;
    for (int j = 0; j < NN; ++j)
      if (adjm[i * 129 + j] != 0.f)
        m = fmaxf(m, lrelu(f1i + xls[j] * s2 + t2));
    float ssum = 0.f, ps = 0.f;
    for (int j = 0; j < NN; ++j)
      if (adjm[i * 129 + j] != 0.f) {
        const float wgt = __expf(lrelu(f1i + xls[j] * s2 + t2) - m);
        ssum += wgt; ps += wgt * xls[j];
      }
    p[i] = ps / ssum;
  }
  __syncthreads();
  if (tid < NN) {
    const int i = tid;
    float xg1[16];
#pragma unroll
    for (int f = 0; f < 16; ++f) {
      const float ov = p[i] * u[f] + v[f];
      xg1[f] = ov > 0.f ? ov : expm1f(ov);
    }
    float wrow[8];
#pragma unroll
    for (int f2 = 0; f2 < 8; ++f2) wrow[f2] = 0.f;
#pragma unroll
    for (int f = 0; f < 16; ++f) {
      const float xv = xg1[f];
#pragma unroll
      for (int f2 = 0; f2 < 8; ++f2) wrow[f2] += xv * W2[f * 8 + f2];
    }
    float fb1 = 0.f, fb2 = 0.f;
#pragma unroll
    for (int f2 = 0; f2 < 8; ++f2) {
      Wh2[i][f2] = wrow[f2];
      fb1 += wrow[f2] * a2[f2];
      fb2 += wrow[f2] * a2[8 + f2];
    }
    f1b[i] = fb1; f2b[i] = fb2;
  }
  __syncthreads();
  if (tid < NN) {
    const int i = tid;
    const float fi = f1b[i];
    float m = -1e30f;
    for (int j = 0; j < NN; ++j)
      if (adjm[i * 129 + j] != 0.f)
        m = fmaxf(m, lrelu(fi + f2b[j]));
    float ssum = 0.f;
    float o[8];
#pragma unroll
    for (int f2 = 0; f2 < 8; ++f2) o[f2] = 0.f;
    for (int j = 0; j < NN; ++j)
      if (adjm[i * 129 + j] != 0.f) {
        const float wgt = __expf(lrelu(fi + f2b[j]) - m);
        ssum += wgt;
#pragma unroll
        for (int f2 = 0; f2 < 8; ++f2) o[f2] += wgt * Wh2[j][f2];
      }
    const float inv = 1.f / ssum;
#pragma unroll
    for (int f2 = 0; f2 < 8; ++f2)
      xg_out[b * (NN * 8) + i * 8 + f2] = o[f2] * inv;
  }
}

// ---------------------------------------------------------------------------
// lstm_heads (structure Z): 2-group quad-butterfly 2-layer LSTM scan + heads.
// 4 blocks x 512 threads (8 waves = exactly 2/EU).
//   group0 (waves 0-3): Whh0 slice (64 fl)        -> L0 step t,   owns c0
//   group1 (waves 4-7): Wih1+Whh1 slices (128 fl) -> L1 step t-1, owns c1
// vs R6: P1 LDS round-trip eliminated (L1 computes its full 128-dot from
// h0/h1 directly), overhead replication 3 waves -> 2 per SIMD, 1 barrier/step.
// waves_per_eu(2,2): unified budget 512/2 = 256 regs/wave; grp1's demand
// ~190 fits. (R6 evidence: the MAX waves/EU is the binding pressure knob.)
// ---------------------------------------------------------------------------
__global__ __attribute__((amdgpu_flat_work_group_size(512, 512),
                          amdgpu_waves_per_eu(2, 2)))
void lstm_heads(
    const float* __restrict__ X0T, const float* __restrict__ Whh0,
    const float* __restrict__ Wih1, const float* __restrict__ Whh1,
    const float* __restrict__ bih1, const float* __restrict__ bhh1,
    const float* __restrict__ xg,
    const float* __restrict__ dw1, const float* __restrict__ db1,
    const float* __restrict__ dw2, const float* __restrict__ db2,
    const float* __restrict__ rw1, const float* __restrict__ rb1,
    const float* __restrict__ rw2, const float* __restrict__ rb2,
    const float* __restrict__ vw1, const float* __restrict__ vb1,
    const float* __restrict__ vw2, const float* __restrict__ vb2,
    float* __restrict__ out)
{
  const int b   = blockIdx.x;
  const int t   = threadIdx.x;
  const bool g1 = (t >= 256);        // wave-uniform group split
  const int r   = t & 255;
  const int uu  = r >> 2, q2 = r & 3;

  __shared__ __align__(16) float hb[2][2][HID];   // [buf][layer][unit]
  __shared__ float cbuf[1088];
  __shared__ float hidc[96];

  // grp0: wA = Whh0 slice. grp1: wA = Wih1 slice, wB = Whh1 slice.
  float4 wA[4][4], wB[4][4];
#pragma unroll
  for (int j = 0; j < 4; ++j) {
    const int row = (uu + 64 * j) * HID + 16 * q2;
#pragma unroll
    for (int c = 0; c < 4; ++c) {
      wA[j][c] = *reinterpret_cast<const float4*>((g1 ? Wih1 : Whh0) + row + 4 * c);
      wB[j][c] = g1 ? *reinterpret_cast<const float4*>(Whh1 + row + 4 * c)
                    : make_float4(0.f, 0.f, 0.f, 0.f);
    }
    pin4(wA[j][0]); pin4(wA[j][1]); pin4(wA[j][2]); pin4(wA[j][3]);
    pin4(wB[j][0]); pin4(wB[j][1]); pin4(wB[j][2]); pin4(wB[j][3]);
  }
  float4 b1v = make_float4(0.f, 0.f, 0.f, 0.f);
  if (g1) {
    b1v.x = bih1[uu]       + bhh1[uu];
    b1v.y = bih1[uu + 64]  + bhh1[uu + 64];
    b1v.z = bih1[uu + 128] + bhh1[uu + 128];
    b1v.w = bih1[uu + 192] + bhh1[uu + 192];
  }

  if (t < 256) reinterpret_cast<float*>(hb)[t] = 0.f;   // both buffers
  float cst = 0.f;                    // c0 (grp0) / c1 (grp1), per-quad redundant
  const float* X0b = X0T + b * G4 + uu * 4;
  float4 cur = make_float4(0.f, 0.f, 0.f, 0.f);
  if (!g1) cur = *reinterpret_cast<const float4*>(X0b);
  __syncthreads();

  // Iter TT: grp0 -> h0[TT] from h0[TT-1],X0[TT]; grp1 -> h1[TT-1] from
  // h0[TT-1],h1[TT-2]. Buf TT&1 holds {h0[TT-1], h1[TT-2]}; writes go to 1-RB.
#define LSTM_STEP(TT, RB, WB)                                                  \
  do {                                                                         \
    const float4* hp0 = reinterpret_cast<const float4*>(&hb[RB][0][0]);        \
    const float4* hp1 = reinterpret_cast<const float4*>(&hb[RB][1][0]);        \
    float4 hq0[4], hq1[4];                                                     \
    hq0[0] = hp0[4 * q2 + 0]; hq0[1] = hp0[4 * q2 + 1];                        \
    hq0[2] = hp0[4 * q2 + 2]; hq0[3] = hp0[4 * q2 + 3];                        \
    if (g1) {                                                                  \
      hq1[0] = hp1[4 * q2 + 0]; hq1[1] = hp1[4 * q2 + 1];                      \
      hq1[2] = hp1[4 * q2 + 2]; hq1[3] = hp1[4 * q2 + 3];                      \
    }                                                                          \
    float4 nxt = cur;                                                          \
    if (!g1 && (TT) + 1 < SEQ)                                                 \
      nxt = *reinterpret_cast<const float4*>(X0b + ((TT) + 1) * (BATCH * G4)); \
    float A0 = dotacc(wA[0], hq0, 0.f);                                        \
    float A1 = dotacc(wA[1], hq0, 0.f);                                        \
    float A2 = dotacc(wA[2], hq0, 0.f);                                        \
    float A3 = dotacc(wA[3], hq0, 0.f);                                        \
    if (g1) {                                                                  \
      A0 = dotacc(wB[0], hq1, A0);                                             \
      A1 = dotacc(wB[1], hq1, A1);                                             \
      A2 = dotacc(wB[2], hq1, A2);                                             \
      A3 = dotacc(wB[3], hq1, A3);                                             \
    }                                                                          \
    const float S0 = qsum(A0), S1 = qsum(A1), S2 = qsum(A2), S3 = qsum(A3);    \
    if (!g1) {                                                                 \
      if ((TT) < SEQ) {                                                        \
        const float gi = fsigm(S0 + cur.x);                                    \
        const float gf = fsigm(S1 + cur.y);                                    \
        const float gg = ftanh(S2 + cur.z);                                    \
        const float go = fsigm(S3 + cur.w);                                    \
        cst = fmaf(gf, cst, gi * gg);                                          \
        if (q2 == 0) hb[WB][0][uu] = go * ftanh(cst);                          \
      }                                                                        \
    } else {                                                                   \
      if ((TT) >= 1 && (TT) <= SEQ) {                                          \
        const float gi = fsigm(S0 + b1v.x);                                    \
        const float gf = fsigm(S1 + b1v.y);                                    \
        const float gg = ftanh(S2 + b1v.z);                                    \
        const float go = fsigm(S3 + b1v.w);                                    \
        cst = fmaf(gf, cst, gi * gg);                                          \
        if (q2 == 0) hb[WB][1][uu] = go * ftanh(cst);                          \
      }                                                                        \
    }                                                                          \
    cur = nxt;                                                                 \
    __syncthreads();                                                           \
  } while (0)

  for (int tt = 0; tt < SEQ + 2; tt += 2) {   // TT = 0..513
    LSTM_STEP(tt, 0, 1);
    LSTM_STEP(tt + 1, 1, 0);
  }
#undef LSTM_STEP
  // grp1's last active write (TT=SEQ, even, WB=1): hb[1][1][*] = h1[SEQ-1].

  // ---------------- fused heads: c = [h1(64) | xg_b(1024)] ----------------
  if (t < 64) cbuf[t] = hb[1][1][t];
  for (int k = t; k < 1024; k += 512) cbuf[64 + k] = xg[b * 1024 + k];
  __syncthreads();
  if (t < 96) {
    const int head = t >> 5, h = t & 31;
    const float* w1 = (head == 0) ? dw1 : (head == 1) ? rw1 : vw1;
    const float* b1 = (head == 0) ? db1 : (head == 1) ? rb1 : vb1;
    float a0 = 0.f, a1v = 0.f, a2v = 0.f, a3v = 0.f;
    for (int k = 0; k < 1088; k += 4) {
      a0  = fmaf(cbuf[k],     w1[k * 32 + h],       a0);
      a1v = fmaf(cbuf[k + 1], w1[(k + 1) * 32 + h], a1v);
      a2v = fmaf(cbuf[k + 2], w1[(k + 2) * 32 + h], a2v);
      a3v = fmaf(cbuf[k + 3], w1[(k + 3) * 32 + h], a3v);
    }
    hidc[head * 32 + h] = fmaxf(b1[h] + ((a0 + a1v) + (a2v + a3v)), 0.f);
  }
  __syncthreads();
  if (t < 4) {
    const int head2 = (t < 2) ? t : 2;
    const int o = (t < 2) ? 0 : (t - 2);
    const int odim = (t < 2) ? 1 : 2;
    const float* w2  = (head2 == 0) ? dw2 : (head2 == 1) ? rw2 : vw2;
    const float* b2p = (head2 == 0) ? db2 : (head2 == 1) ? rb2 : vb2;
    float acc = b2p[o];
    for (int hh = 0; hh < 32; ++hh)
      acc = fmaf(hidc[head2 * 32 + hh], w2[hh * odim + o], acc);
    const int off = (t == 0) ? b : (t == 1) ? (4 + b) : (8 + 2 * b + o);
    out[off] = acc;   // [dir(4) | ret(4) | vol(4x2)] flat
  }
}

// ---------------------------------------------------------------------------
extern "C" void kernel_launch(void* const* d_in, const int* in_sizes, int n_in,
                              void* d_out, int out_size, void* d_ws, size_t ws_size,
                              hipStream_t stream) {
  const float* x     = (const float*)d_in[0];
  const int*   adj   = (const int*)  d_in[1];
  const float* emb_w = (const float*)d_in[2];
  const float* emb_b = (const float*)d_in[3];
  const float* g1W   = (const float*)d_in[4];
  const float* g1a   = (const float*)d_in[5];
  const float* g2W   = (const float*)d_in[6];
  const float* g2a   = (const float*)d_in[7];
  const float* Wih0  = (const float*)d_in[8];
  const float* Whh0  = (const float*)d_in[9];
  const float* bih0  = (const float*)d_in[10];
  const float* bhh0  = (const float*)d_in[11];
  const float* Wih1  = (const float*)d_in[12];
  const float* Whh1  = (const float*)d_in[13];
  const float* bih1  = (const float*)d_in[14];
  const float* bhh1  = (const float*)d_in[15];
  const float* dw1 = (const float*)d_in[16]; const float* db1 = (const float*)d_in[17];
  const float* dw2 = (const float*)d_in[18]; const float* db2 = (const float*)d_in[19];
  const float* rw1 = (const float*)d_in[20]; const float* rb1 = (const float*)d_in[21];
  const float* rw2 = (const float*)d_in[22]; const float* rb2 = (const float*)d_in[23];
  const float* vw1 = (const float*)d_in[24]; const float* vb1 = (const float*)d_in[25];
  const float* vw2 = (const float*)d_in[26]; const float* vb2 = (const float*)d_in[27];

  float* ws = (float*)d_ws;
  float* X0 = ws;                         // SEQ*BATCH*256 floats = 2 MB (transposed)
  float* xg = ws + SEQ * BATCH * G4;      // 4096 floats
  float* out = (float*)d_out;

  hipLaunchKernelGGL(prep_kernel, dim3(132), dim3(512), 0, stream,
                     x, Wih0, bih0, bhh0, X0,
                     adj, emb_w, emb_b, g1W, g1a, g2W, g2a, xg);
  hipLaunchKernelGGL(lstm_heads, dim3(BATCH), dim3(512), 0, stream,
                     X0, Whh0, Wih1, Whh1, bih1, bhh1, xg,
                     dw1, db1, dw2, db2, rw1, rb1, rw2, rb2,
                     vw1, vb1, vw2, vb2, out);
}

// Round 9
// 470.422 us; speedup vs baseline: 1.5570x; 1.2613x over previous
//
#include <hip/hip_runtime.h>

#define SEQ   512
#define BATCH 4
#define NN    128
#define HID   64
#define G4    256   // 4*HID gates per layer

// Fast activations: v_exp_f32 + v_rcp_f32 (abs err ~1e-6, threshold is 1e-3)
__device__ __forceinline__ float frcp(float x)  { return __builtin_amdgcn_rcpf(x); }
__device__ __forceinline__ float fsigm(float x) { return frcp(1.f + __expf(-x)); }
__device__ __forceinline__ float ftanh(float x) { return 1.f - 2.f * frcp(1.f + __expf(2.f * x)); }
__device__ __forceinline__ float lrelu(float x) { return x > 0.f ? x : 0.2f * x; }
__device__ __forceinline__ float dot4f(float4 w, float4 h) {
  return fmaf(w.x, h.x, fmaf(w.y, h.y, fmaf(w.z, h.z, w.w * h.w)));
}
// "+v" pin: forces the 4 components into ARCH VGPRs at this point.
// R5 lesson: in-loop pins + tiny budget (8-wave target) = scratch churn.
// R6 lesson: waves_per_eu(3,3) sets a 170-reg budget but the RA parks
// weights in AGPRs (VALU can't read them -> v_accvgpr_read tax ~64/step).
// R9: BOTH together — 170-reg budget + in-loop "+v" pins -> demand (~115)
// fits in arch VGPRs, pins keep the class, no copies, no churn.
__device__ __forceinline__ void pin4(float4& v) {
  asm volatile("" : "+v"(v.x), "+v"(v.y), "+v"(v.z), "+v"(v.w));
}
// Quad butterfly sum via self-inverse quad_perm: 0xB1={1,0,3,2}, 0x4E={2,3,0,1}.
__device__ __forceinline__ float qsum(float x) {
  x += __int_as_float(__builtin_amdgcn_update_dpp(
      0, __float_as_int(x), 0xB1, 0xF, 0xF, true));
  x += __int_as_float(__builtin_amdgcn_update_dpp(
      0, __float_as_int(x), 0x4E, 0xF, 0xF, true));
  return x;
}
__device__ __forceinline__ float dotacc(const float4* w, const float4* h, float a) {
#pragma unroll
  for (int c = 0; c < 4; ++c) {
    a = fmaf(w[c].x, h[c].x, a);
    a = fmaf(w[c].y, h[c].y, a);
    a = fmaf(w[c].z, h[c].z, a);
    a = fmaf(w[c].w, h[c].w, a);
  }
  return a;
}

// ---------------------------------------------------------------------------
// prep_kernel (verified R4-R8): blocks [0,128) X0 GEMM (transposed store:
// (t,b,unit) -> 4 contiguous gate values i,f,g,o); blocks [128,132) GAT.
// ---------------------------------------------------------------------------
__global__ __launch_bounds__(512) void prep_kernel(
    const float* __restrict__ x, const float* __restrict__ Wih0,
    const float* __restrict__ bih0, const float* __restrict__ bhh0,
    float* __restrict__ X0,
    const int* __restrict__ adj, const float* __restrict__ emb_w,
    const float* __restrict__ emb_b,
    const float* __restrict__ W1, const float* __restrict__ a1,
    const float* __restrict__ W2, const float* __restrict__ a2,
    float* __restrict__ xg_out)
{
  const int tid = threadIdx.x;
  if (blockIdx.x < 128) {
    __shared__ __align__(16) float xls[NN];
    const int g = tid >> 1, half = tid & 1;
    float4 w4[16];
    {
      const float4* wp = reinterpret_cast<const float4*>(Wih0 + g * NN + half * 64);
#pragma unroll
      for (int i = 0; i < 16; ++i) w4[i] = wp[i];
    }
    const float bsum = bih0[g] + bhh0[g];
    const int r0 = blockIdx.x * 16;
    for (int r = r0; r < r0 + 16; ++r) {
      const int tt = r >> 2, b = r & 3;
      if (tid < NN) xls[tid] = x[(b * SEQ + tt) * NN + tid];
      __syncthreads();
      const float4* hp = reinterpret_cast<const float4*>(&xls[half * 64]);
      float p0 = 0.f, p1 = 0.f, p2 = 0.f, p3 = 0.f;
#pragma unroll
      for (int k = 0; k < 16; k += 4) {
        p0 += dot4f(w4[k],     hp[k]);
        p1 += dot4f(w4[k + 1], hp[k + 1]);
        p2 += dot4f(w4[k + 2], hp[k + 2]);
        p3 += dot4f(w4[k + 3], hp[k + 3]);
      }
      float p = (p0 + p1) + (p2 + p3);
      p += __shfl_xor(p, 1);
      if (half == 0) X0[r * G4 + (g & 63) * 4 + (g >> 6)] = p + bsum;
      __syncthreads();
    }
    return;
  }
  const int b = blockIdx.x - 128;
  __shared__ float adjm[NN * 129];
  __shared__ __align__(16) float xls[NN];
  __shared__ float u[16], v[16];
  __shared__ float Wh2[NN][9];
  __shared__ float f1b[NN], f2b[NN];
  __shared__ float p[NN];

  for (int idx = tid; idx < NN * NN; idx += 512)
    adjm[(idx >> 7) * 129 + (idx & 127)] = (adj[idx] > 0) ? 1.f : 0.f;
  if (tid < NN) xls[tid] = x[(b * SEQ + (SEQ - 1)) * NN + tid];
  if (tid < 16) {
    float uu = 0.f, vv = 0.f;
    for (int fp = 0; fp < 16; ++fp) {
      uu += emb_w[fp] * W1[fp * 16 + tid];
      vv += emb_b[fp] * W1[fp * 16 + tid];
    }
    u[tid] = uu; v[tid] = vv;
  }
  __syncthreads();
  float s1 = 0.f, t1 = 0.f, s2 = 0.f, t2 = 0.f;
  for (int f = 0; f < 16; ++f) {
    s1 += u[f] * a1[f];      t1 += v[f] * a1[f];
    s2 += u[f] * a1[16 + f]; t2 += v[f] * a1[16 + f];
  }
  if (tid < NN) {
    const int i = tid;
    const float f1i = xls[i] * s1 + t1;
    float m = -1e30f;
    for (int j = 0; j < NN; ++j)
      if (adjm[i * 129 + j] != 0.f)
        m = fmaxf(m, lrelu(f1i + xls[j] * s2 + t2));
    float ssum = 0.f, ps = 0.f;
    for (int j = 0; j < NN; ++j)
      if (adjm[i * 129 + j] != 0.f) {
        const float wgt = __expf(lrelu(f1i + xls[j] * s2 + t2) - m);
        ssum += wgt; ps += wgt * xls[j];
      }
    p[i] = ps / ssum;
  }
  __syncthreads();
  if (tid < NN) {
    const int i = tid;
    float xg1[16];
#pragma unroll
    for (int f = 0; f < 16; ++f) {
      const float ov = p[i] * u[f] + v[f];
      xg1[f] = ov > 0.f ? ov : expm1f(ov);
    }
    float wrow[8];
#pragma unroll
    for (int f2 = 0; f2 < 8; ++f2) wrow[f2] = 0.f;
#pragma unroll
    for (int f = 0; f < 16; ++f) {
      const float xv = xg1[f];
#pragma unroll
      for (int f2 = 0; f2 < 8; ++f2) wrow[f2] += xv * W2[f * 8 + f2];
    }
    float fb1 = 0.f, fb2 = 0.f;
#pragma unroll
    for (int f2 = 0; f2 < 8; ++f2) {
      Wh2[i][f2] = wrow[f2];
      fb1 += wrow[f2] * a2[f2];
      fb2 += wrow[f2] * a2[8 + f2];
    }
    f1b[i] = fb1; f2b[i] = fb2;
  }
  __syncthreads();
  if (tid < NN) {
    const int i = tid;
    const float fi = f1b[i];
    float m = -1e30f;
    for (int j = 0; j < NN; ++j)
      if (adjm[i * 129 + j] != 0.f)
        m = fmaxf(m, lrelu(fi + f2b[j]));
    float ssum = 0.f;
    float o[8];
#pragma unroll
    for (int f2 = 0; f2 < 8; ++f2) o[f2] = 0.f;
    for (int j = 0; j < NN; ++j)
      if (adjm[i * 129 + j] != 0.f) {
        const float wgt = __expf(lrelu(fi + f2b[j]) - m);
        ssum += wgt;
#pragma unroll
        for (int f2 = 0; f2 < 8; ++f2) o[f2] += wgt * Wh2[j][f2];
      }
    const float inv = 1.f / ssum;
#pragma unroll
    for (int f2 = 0; f2 < 8; ++f2)
      xg_out[b * (NN * 8) + i * 8 + f2] = o[f2] * inv;
  }
}

// ---------------------------------------------------------------------------
// lstm_heads (R6 structure + in-loop arch-VGPR pins): 3-group quad-butterfly
// 2-layer LSTM scan + fused heads. 4 blocks x 768 threads (12 waves = 3/EU).
//   group0 (waves 0-3):  Whh0 slice -> L0 gates, owns c0, writes h0[t]
//   group1 (waves 4-7):  Wih1 slice -> L1 ih-partials -> P1[t] (dbuf)
//   group2 (waves 8-11): Whh1 slice + P1[t-1] + bias -> L1 step t-2, owns c1
// ONE barrier/step. waves_per_eu(3,3): 512/3=170-reg pressure budget (R6
// evidence: MAX waves/EU is the binding knob). In-loop "+v" pins keep the
// 64 weight floats in ARCH VGPRs (R6 parked them in AGPRs: ~64
// v_accvgpr_read/wave/step = the gap between 1450 measured and ~1070
// necessary cyc/step).
// ---------------------------------------------------------------------------
__global__ __attribute__((amdgpu_flat_work_group_size(768, 768),
                          amdgpu_waves_per_eu(3, 3)))
void lstm_heads(
    const float* __restrict__ X0T, const float* __restrict__ Whh0,
    const float* __restrict__ Wih1, const float* __restrict__ Whh1,
    const float* __restrict__ bih1, const float* __restrict__ bhh1,
    const float* __restrict__ xg,
    const float* __restrict__ dw1, const float* __restrict__ db1,
    const float* __restrict__ dw2, const float* __restrict__ db2,
    const float* __restrict__ rw1, const float* __restrict__ rb1,
    const float* __restrict__ rw2, const float* __restrict__ rb2,
    const float* __restrict__ vw1, const float* __restrict__ vb1,
    const float* __restrict__ vw2, const float* __restrict__ vb2,
    float* __restrict__ out)
{
  const int b   = blockIdx.x;
  const int t   = threadIdx.x;
  const int grp = t >> 8;            // 0,1,2 (wave-aligned)
  const int r   = t & 255;           // == uu*4 + q2
  const int uu  = r >> 2, q2 = r & 3;

  __shared__ __align__(16) float hb[2][2][HID];   // [buf][layer][unit]
  __shared__ __align__(16) float P1[2][G4];       // dbuf ih-partials
  __shared__ float cbuf[1088];
  __shared__ float hidc[96];

  const float* Wsrc = (grp == 0) ? Whh0 : (grp == 1) ? Wih1 : Whh1;
  float4 w[4][4];
#pragma unroll
  for (int j = 0; j < 4; ++j) {
    const int row = (uu + 64 * j) * HID + 16 * q2;
#pragma unroll
    for (int c = 0; c < 4; ++c)
      w[j][c] = *reinterpret_cast<const float4*>(Wsrc + row + 4 * c);
  }
  float4 b1v = make_float4(0.f, 0.f, 0.f, 0.f);
  if (grp == 2) {
    b1v.x = bih1[uu]       + bhh1[uu];
    b1v.y = bih1[uu + 64]  + bhh1[uu + 64];
    b1v.z = bih1[uu + 128] + bhh1[uu + 128];
    b1v.w = bih1[uu + 192] + bhh1[uu + 192];
  }

  if (t < 256) reinterpret_cast<float*>(hb)[t] = 0.f;   // both buffers
  float cst = 0.f;                    // c0 (grp0) / c1 (grp2), per-quad redundant
  const float* X0b = X0T + b * G4 + uu * 4;
  float4 cur = make_float4(0.f, 0.f, 0.f, 0.f);
  if (grp == 0) cur = *reinterpret_cast<const float4*>(X0b);
  __syncthreads();

  // Pipeline (iter TT): grp0 -> h0[TT]; grp1 -> P1[TT] = Wih1*h0[TT-1];
  // grp2 -> L1 step TT-2 (reads P1[TT-1], h1[TT-3]) -> h1[TT-2].
#define LSTM_STEP(TT, RB, WB)                                                  \
  do {                                                                         \
    const float4* hp = reinterpret_cast<const float4*>(                        \
        (grp == 2) ? &hb[RB][1][0] : &hb[RB][0][0]);                           \
    float4 hq[4];                                                              \
    hq[0] = hp[4 * q2 + 0]; hq[1] = hp[4 * q2 + 1];                            \
    hq[2] = hp[4 * q2 + 2]; hq[3] = hp[4 * q2 + 3];                            \
    float4 p1v = make_float4(0.f, 0.f, 0.f, 0.f);                              \
    if (grp == 2) p1v = *reinterpret_cast<const float4*>(&P1[1 - (RB)][uu * 4]); \
    float4 nxt = cur;                                                          \
    if (grp == 0 && (TT) + 1 < SEQ)                                            \
      nxt = *reinterpret_cast<const float4*>(X0b + ((TT) + 1) * (BATCH * G4)); \
    float A0 = dotacc(w[0], hq, 0.f);                                          \
    float A1 = dotacc(w[1], hq, 0.f);                                          \
    float A2 = dotacc(w[2], hq, 0.f);                                          \
    float A3 = dotacc(w[3], hq, 0.f);                                          \
    const float S0 = qsum(A0), S1 = qsum(A1), S2 = qsum(A2), S3 = qsum(A3);    \
    if (grp == 0) {                                                            \
      if ((TT) < SEQ) {                                                        \
        const float gi = fsigm(S0 + cur.x);                                    \
        const float gf = fsigm(S1 + cur.y);                                    \
        const float gg = ftanh(S2 + cur.z);                                    \
        const float go = fsigm(S3 + cur.w);                                    \
        cst = fmaf(gf, cst, gi * gg);                                          \
        if (q2 == 0) hb[WB][0][uu] = go * ftanh(cst);                          \
      }                                                                        \
    } else if (grp == 1) {                                                     \
      if ((TT) >= 1 && (TT) <= SEQ) {                                          \
        const float sel = (q2 == 0) ? S0 : (q2 == 1) ? S1 : (q2 == 2) ? S2 : S3; \
        P1[RB][r] = sel;                                                       \
      }                                                                        \
    } else {                                                                   \
      if ((TT) >= 2) {                                                         \
        const float gi = fsigm(S0 + p1v.x + b1v.x);                            \
        const float gf = fsigm(S1 + p1v.y + b1v.y);                            \
        const float gg = ftanh(S2 + p1v.z + b1v.z);                            \
        const float go = fsigm(S3 + p1v.w + b1v.w);                            \
        cst = fmaf(gf, cst, gi * gg);                                          \
        if (q2 == 0) hb[WB][1][uu] = go * ftanh(cst);                          \
      }                                                                        \
    }                                                                          \
    cur = nxt;                                                                 \
    __syncthreads();                                                           \
  } while (0)

  for (int tt = 0; tt < SEQ + 2; tt += 2) {   // TT = 0..513
    // In-loop arch-VGPR pins (once per 2 steps): with the 170-reg budget
    // the weights fit in "v" class; pins prevent AGPR parking/remat.
#pragma unroll
    for (int j = 0; j < 4; ++j) {
      pin4(w[j][0]); pin4(w[j][1]); pin4(w[j][2]); pin4(w[j][3]);
    }
    LSTM_STEP(tt, 0, 1);
    LSTM_STEP(tt + 1, 1, 0);
  }
#undef LSTM_STEP
  // grp2's last write (TT=513, WB=0): hb[0][1][*] = h1[SEQ-1] = xl_out.

  // ---------------- fused heads: c = [h1(64) | xg_b(1024)] ----------------
  if (t < 64) cbuf[t] = hb[0][1][t];
  for (int k = t; k < 1024; k += 768) cbuf[64 + k] = xg[b * 1024 + k];
  __syncthreads();
  if (t < 96) {
    const int head = t >> 5, h = t & 31;
    const float* w1 = (head == 0) ? dw1 : (head == 1) ? rw1 : vw1;
    const float* b1 = (head == 0) ? db1 : (head == 1) ? rb1 : vb1;
    float a0 = 0.f, a1v = 0.f, a2v = 0.f, a3v = 0.f;
    for (int k = 0; k < 1088; k += 4) {
      a0  = fmaf(cbuf[k],     w1[k * 32 + h],       a0);
      a1v = fmaf(cbuf[k + 1], w1[(k + 1) * 32 + h], a1v);
      a2v = fmaf(cbuf[k + 2], w1[(k + 2) * 32 + h], a2v);
      a3v = fmaf(cbuf[k + 3], w1[(k + 3) * 32 + h], a3v);
    }
    hidc[head * 32 + h] = fmaxf(b1[h] + ((a0 + a1v) + (a2v + a3v)), 0.f);
  }
  __syncthreads();
  if (t < 4) {
    const int head2 = (t < 2) ? t : 2;
    const int o = (t < 2) ? 0 : (t - 2);
    const int odim = (t < 2) ? 1 : 2;
    const float* w2  = (head2 == 0) ? dw2 : (head2 == 1) ? rw2 : vw2;
    const float* b2p = (head2 == 0) ? db2 : (head2 == 1) ? rb2 : vb2;
    float acc = b2p[o];
    for (int hh = 0; hh < 32; ++hh)
      acc = fmaf(hidc[head2 * 32 + hh], w2[hh * odim + o], acc);
    const int off = (t == 0) ? b : (t == 1) ? (4 + b) : (8 + 2 * b + o);
    out[off] = acc;   // [dir(4) | ret(4) | vol(4x2)] flat
  }
}

// ---------------------------------------------------------------------------
extern "C" void kernel_launch(void* const* d_in, const int* in_sizes, int n_in,
                              void* d_out, int out_size, void* d_ws, size_t ws_size,
                              hipStream_t stream) {
  const float* x     = (const float*)d_in[0];
  const int*   adj   = (const int*)  d_in[1];
  const float* emb_w = (const float*)d_in[2];
  const float* emb_b = (const float*)d_in[3];
  const float* g1W   = (const float*)d_in[4];
  const float* g1a   = (const float*)d_in[5];
  const float* g2W   = (const float*)d_in[6];
  const float* g2a   = (const float*)d_in[7];
  const float* Wih0  = (const float*)d_in[8];
  const float* Whh0  = (const float*)d_in[9];
  const float* bih0  = (const float*)d_in[10];
  const float* bhh0  = (const float*)d_in[11];
  const float* Wih1  = (const float*)d_in[12];
  const float* Whh1  = (const float*)d_in[13];
  const float* bih1  = (const float*)d_in[14];
  const float* bhh1  = (const float*)d_in[15];
  const float* dw1 = (const float*)d_in[16]; const float* db1 = (const float*)d_in[17];
  const float* dw2 = (const float*)d_in[18]; const float* db2 = (const float*)d_in[19];
  const float* rw1 = (const float*)d_in[20]; const float* rb1 = (const float*)d_in[21];
  const float* rw2 = (const float*)d_in[22]; const float* rb2 = (const float*)d_in[23];
  const float* vw1 = (const float*)d_in[24]; const float* vb1 = (const float*)d_in[25];
  const float* vw2 = (const float*)d_in[26]; const float* vb2 = (const float*)d_in[27];

  float* ws = (float*)d_ws;
  float* X0 = ws;                         // SEQ*BATCH*256 floats = 2 MB (transposed)
  float* xg = ws + SEQ * BATCH * G4;      // 4096 floats
  float* out = (float*)d_out;

  hipLaunchKernelGGL(prep_kernel, dim3(132), dim3(512), 0, stream,
                     x, Wih0, bih0, bhh0, X0,
                     adj, emb_w, emb_b, g1W, g1a, g2W, g2a, xg);
  hipLaunchKernelGGL(lstm_heads, dim3(BATCH), dim3(768), 0, stream,
                     X0, Whh0, Wih1, Whh1, bih1, bhh1, xg,
                     dw1, db1, dw2, db2, rw1, rb1, rw2, rb2,
                     vw1, vb1, vw2, vb2, out);
}

// Round 10
// 465.859 us; speedup vs baseline: 1.5723x; 1.0098x over previous
//
#include <hip/hip_runtime.h>

#define SEQ   512
#define BATCH 4
#define NN    128
#define HID   64
#define G4    256   // 4*HID gates per layer

// Fast activations: v_exp_f32 + v_rcp_f32 (abs err ~1e-6, threshold is 1e-3)
__device__ __forceinline__ float frcp(float x)  { return __builtin_amdgcn_rcpf(x); }
__device__ __forceinline__ float fsigm(float x) { return frcp(1.f + __expf(-x)); }
__device__ __forceinline__ float ftanh(float x) { return 1.f - 2.f * frcp(1.f + __expf(2.f * x)); }
__device__ __forceinline__ float lrelu(float x) { return x > 0.f ? x : 0.2f * x; }
__device__ __forceinline__ float dot4f(float4 w, float4 h) {
  return fmaf(w.x, h.x, fmaf(w.y, h.y, fmaf(w.z, h.z, w.w * h.w)));
}
// "+v" pin (init-time): blocks load-sinking/remat. Only effective when the
// pressure budget is large enough that the RA doesn't spill (R4/R5 lessons).
__device__ __forceinline__ void pin4(float4& v) {
  asm volatile("" : "+v"(v.x), "+v"(v.y), "+v"(v.z), "+v"(v.w));
}
// Quad butterfly sum via self-inverse quad_perm: 0xB1={1,0,3,2}, 0x4E={2,3,0,1}.
__device__ __forceinline__ float qsum(float x) {
  x += __int_as_float(__builtin_amdgcn_update_dpp(
      0, __float_as_int(x), 0xB1, 0xF, 0xF, true));
  x += __int_as_float(__builtin_amdgcn_update_dpp(
      0, __float_as_int(x), 0x4E, 0xF, 0xF, true));
  return x;
}
__device__ __forceinline__ float dotacc(const float4* w, const float4* h, float a) {
#pragma unroll
  for (int c = 0; c < 4; ++c) {
    a = fmaf(w[c].x, h[c].x, a);
    a = fmaf(w[c].y, h[c].y, a);
    a = fmaf(w[c].z, h[c].z, a);
    a = fmaf(w[c].w, h[c].w, a);
  }
  return a;
}

// ---------------------------------------------------------------------------
// prep_kernel: blocks [0,128) X0 GEMM (transposed store), [128,132) GAT.
// R10 fix: waves_per_eu(2,2). prep had NO max-waves attr -> default 8-wave
// pressure target -> 64-reg cap -> the 64 weight floats/thread spilled to
// scratch and reloaded all 16 row-iterations (2 MB/block scratch churn,
// ~150 us = the constant total-minus-lstm residue of R2-R9). 132 blocks on
// 256 CUs = 1 block/CU = 8 waves = 2/EU, so (2,2) is exact: 256-reg budget,
// ~85-reg demand, weights stay resident. Init pins block load-sinking.
// ---------------------------------------------------------------------------
__global__ __attribute__((amdgpu_flat_work_group_size(512, 512),
                          amdgpu_waves_per_eu(2, 2)))
void prep_kernel(
    const float* __restrict__ x, const float* __restrict__ Wih0,
    const float* __restrict__ bih0, const float* __restrict__ bhh0,
    float* __restrict__ X0,
    const int* __restrict__ adj, const float* __restrict__ emb_w,
    const float* __restrict__ emb_b,
    const float* __restrict__ W1, const float* __restrict__ a1,
    const float* __restrict__ W2, const float* __restrict__ a2,
    float* __restrict__ xg_out)
{
  const int tid = threadIdx.x;
  if (blockIdx.x < 128) {
    __shared__ __align__(16) float xls[NN];
    const int g = tid >> 1, half = tid & 1;
    float4 w4[16];
    {
      const float4* wp = reinterpret_cast<const float4*>(Wih0 + g * NN + half * 64);
#pragma unroll
      for (int i = 0; i < 16; ++i) w4[i] = wp[i];
#pragma unroll
      for (int i = 0; i < 16; ++i) pin4(w4[i]);
    }
    const float bsum = bih0[g] + bhh0[g];
    const int r0 = blockIdx.x * 16;
    for (int r = r0; r < r0 + 16; ++r) {
      const int tt = r >> 2, b = r & 3;
      if (tid < NN) xls[tid] = x[(b * SEQ + tt) * NN + tid];
      __syncthreads();
      const float4* hp = reinterpret_cast<const float4*>(&xls[half * 64]);
      float p0 = 0.f, p1 = 0.f, p2 = 0.f, p3 = 0.f;
#pragma unroll
      for (int k = 0; k < 16; k += 4) {
        p0 += dot4f(w4[k],     hp[k]);
        p1 += dot4f(w4[k + 1], hp[k + 1]);
        p2 += dot4f(w4[k + 2], hp[k + 2]);
        p3 += dot4f(w4[k + 3], hp[k + 3]);
      }
      float p = (p0 + p1) + (p2 + p3);
      p += __shfl_xor(p, 1);
      if (half == 0) X0[r * G4 + (g & 63) * 4 + (g >> 6)] = p + bsum;
      __syncthreads();
    }
    return;
  }
  const int b = blockIdx.x - 128;
  __shared__ float adjm[NN * 129];
  __shared__ __align__(16) float xls[NN];
  __shared__ float u[16], v[16];
  __shared__ float Wh2[NN][9];
  __shared__ float f1b[NN], f2b[NN];
  __shared__ float p[NN];

  for (int idx = tid; idx < NN * NN; idx += 512)
    adjm[(idx >> 7) * 129 + (idx & 127)] = (adj[idx] > 0) ? 1.f : 0.f;
  if (tid < NN) xls[tid] = x[(b * SEQ + (SEQ - 1)) * NN + tid];
  if (tid < 16) {
    float uu = 0.f, vv = 0.f;
    for (int fp = 0; fp < 16; ++fp) {
      uu += emb_w[fp] * W1[fp * 16 + tid];
      vv += emb_b[fp] * W1[fp * 16 + tid];
    }
    u[tid] = uu; v[tid] = vv;
  }
  __syncthreads();
  float s1 = 0.f, t1 = 0.f, s2 = 0.f, t2 = 0.f;
  for (int f = 0; f < 16; ++f) {
    s1 += u[f] * a1[f];      t1 += v[f] * a1[f];
    s2 += u[f] * a1[16 + f]; t2 += v[f] * a1[16 + f];
  }
  if (tid < NN) {
    const int i = tid;
    const float f1i = xls[i] * s1 + t1;
    float m = -1e30f;
    for (int j = 0; j < NN; ++j)
      if (adjm[i * 129 + j] != 0.f)
        m = fmaxf(m, lrelu(f1i + xls[j] * s2 + t2));
    float ssum = 0.f, ps = 0.f;
    for (int j = 0; j < NN; ++j)
      if (adjm[i * 129 + j] != 0.f) {
        const float wgt = __expf(lrelu(f1i + xls[j] * s2 + t2) - m);
        ssum += wgt; ps += wgt * xls[j];
      }
    p[i] = ps / ssum;
  }
  __syncthreads();
  if (tid < NN) {
    const int i = tid;
    float xg1[16];
#pragma unroll
    for (int f = 0; f < 16; ++f) {
      const float ov = p[i] * u[f] + v[f];
      xg1[f] = ov > 0.f ? ov : expm1f(ov);
    }
    float wrow[8];
#pragma unroll
    for (int f2 = 0; f2 < 8; ++f2) wrow[f2] = 0.f;
#pragma unroll
    for (int f = 0; f < 16; ++f) {
      const float xv = xg1[f];
#pragma unroll
      for (int f2 = 0; f2 < 8; ++f2) wrow[f2] += xv * W2[f * 8 + f2];
    }
    float fb1 = 0.f, fb2 = 0.f;
#pragma unroll
    for (int f2 = 0; f2 < 8; ++f2) {
      Wh2[i][f2] = wrow[f2];
      fb1 += wrow[f2] * a2[f2];
      fb2 += wrow[f2] * a2[8 + f2];
    }
    f1b[i] = fb1; f2b[i] = fb2;
  }
  __syncthreads();
  if (tid < NN) {
    const int i = tid;
    const float fi = f1b[i];
    float m = -1e30f;
    for (int j = 0; j < NN; ++j)
      if (adjm[i * 129 + j] != 0.f)
        m = fmaxf(m, lrelu(fi + f2b[j]));
    float ssum = 0.f;
    float o[8];
#pragma unroll
    for (int f2 = 0; f2 < 8; ++f2) o[f2] = 0.f;
    for (int j = 0; j < NN; ++j)
      if (adjm[i * 129 + j] != 0.f) {
        const float wgt = __expf(lrelu(fi + f2b[j]) - m);
        ssum += wgt;
#pragma unroll
        for (int f2 = 0; f2 < 8; ++f2) o[f2] += wgt * Wh2[j][f2];
      }
    const float inv = 1.f / ssum;
#pragma unroll
    for (int f2 = 0; f2 < 8; ++f2)
      xg_out[b * (NN * 8) + i * 8 + f2] = o[f2] * inv;
  }
}

// ---------------------------------------------------------------------------
// lstm_heads: UNCHANGED from R9 (equal-best, 311 us, stable). 3-group
// quad-butterfly scan, 4 blocks x 768 threads, waves_per_eu(3,3),
// 1 barrier/step. Known plateau: VALU-issue-bound at ~1450 cyc/step incl.
// ~64 v_accvgpr copies/wave/step (AGPR parking; R8/R9 attempts to remove
// it failed — see session journal).
// ---------------------------------------------------------------------------
__global__ __attribute__((amdgpu_flat_work_group_size(768, 768),
                          amdgpu_waves_per_eu(3, 3)))
void lstm_heads(
    const float* __restrict__ X0T, const float* __restrict__ Whh0,
    const float* __restrict__ Wih1, const float* __restrict__ Whh1,
    const float* __restrict__ bih1, const float* __restrict__ bhh1,
    const float* __restrict__ xg,
    const float* __restrict__ dw1, const float* __restrict__ db1,
    const float* __restrict__ dw2, const float* __restrict__ db2,
    const float* __restrict__ rw1, const float* __restrict__ rb1,
    const float* __restrict__ rw2, const float* __restrict__ rb2,
    const float* __restrict__ vw1, const float* __restrict__ vb1,
    const float* __restrict__ vw2, const float* __restrict__ vb2,
    float* __restrict__ out)
{
  const int b   = blockIdx.x;
  const int t   = threadIdx.x;
  const int grp = t >> 8;            // 0,1,2 (wave-aligned)
  const int r   = t & 255;           // == uu*4 + q2
  const int uu  = r >> 2, q2 = r & 3;

  __shared__ __align__(16) float hb[2][2][HID];   // [buf][layer][unit]
  __shared__ __align__(16) float P1[2][G4];       // dbuf ih-partials
  __shared__ float cbuf[1088];
  __shared__ float hidc[96];

  const float* Wsrc = (grp == 0) ? Whh0 : (grp == 1) ? Wih1 : Whh1;
  float4 w[4][4];
#pragma unroll
  for (int j = 0; j < 4; ++j) {
    const int row = (uu + 64 * j) * HID + 16 * q2;
#pragma unroll
    for (int c = 0; c < 4; ++c)
      w[j][c] = *reinterpret_cast<const float4*>(Wsrc + row + 4 * c);
  }
  float4 b1v = make_float4(0.f, 0.f, 0.f, 0.f);
  if (grp == 2) {
    b1v.x = bih1[uu]       + bhh1[uu];
    b1v.y = bih1[uu + 64]  + bhh1[uu + 64];
    b1v.z = bih1[uu + 128] + bhh1[uu + 128];
    b1v.w = bih1[uu + 192] + bhh1[uu + 192];
  }

  if (t < 256) reinterpret_cast<float*>(hb)[t] = 0.f;   // both buffers
  float cst = 0.f;                    // c0 (grp0) / c1 (grp2), per-quad redundant
  const float* X0b = X0T + b * G4 + uu * 4;
  float4 cur = make_float4(0.f, 0.f, 0.f, 0.f);
  if (grp == 0) cur = *reinterpret_cast<const float4*>(X0b);
  __syncthreads();

  // Pipeline (iter TT): grp0 -> h0[TT]; grp1 -> P1[TT] = Wih1*h0[TT-1];
  // grp2 -> L1 step TT-2 (reads P1[TT-1], h1[TT-3]) -> h1[TT-2].
#define LSTM_STEP(TT, RB, WB)                                                  \
  do {                                                                         \
    const float4* hp = reinterpret_cast<const float4*>(                        \
        (grp == 2) ? &hb[RB][1][0] : &hb[RB][0][0]);                           \
    float4 hq[4];                                                              \
    hq[0] = hp[4 * q2 + 0]; hq[1] = hp[4 * q2 + 1];                            \
    hq[2] = hp[4 * q2 + 2]; hq[3] = hp[4 * q2 + 3];                            \
    float4 p1v = make_float4(0.f, 0.f, 0.f, 0.f);                              \
    if (grp == 2) p1v = *reinterpret_cast<const float4*>(&P1[1 - (RB)][uu * 4]); \
    float4 nxt = cur;                                                          \
    if (grp == 0 && (TT) + 1 < SEQ)                                            \
      nxt = *reinterpret_cast<const float4*>(X0b + ((TT) + 1) * (BATCH * G4)); \
    float A0 = dotacc(w[0], hq, 0.f);                                          \
    float A1 = dotacc(w[1], hq, 0.f);                                          \
    float A2 = dotacc(w[2], hq, 0.f);                                          \
    float A3 = dotacc(w[3], hq, 0.f);                                          \
    const float S0 = qsum(A0), S1 = qsum(A1), S2 = qsum(A2), S3 = qsum(A3);    \
    if (grp == 0) {                                                            \
      if ((TT) < SEQ) {                                                        \
        const float gi = fsigm(S0 + cur.x);                                    \
        const float gf = fsigm(S1 + cur.y);                                    \
        const float gg = ftanh(S2 + cur.z);                                    \
        const float go = fsigm(S3 + cur.w);                                    \
        cst = fmaf(gf, cst, gi * gg);                                          \
        if (q2 == 0) hb[WB][0][uu] = go * ftanh(cst);                          \
      }                                                                        \
    } else if (grp == 1) {                                                     \
      if ((TT) >= 1 && (TT) <= SEQ) {                                          \
        const float sel = (q2 == 0) ? S0 : (q2 == 1) ? S1 : (q2 == 2) ? S2 : S3; \
        P1[RB][r] = sel;                                                       \
      }                                                                        \
    } else {                                                                   \
      if ((TT) >= 2) {                                                         \
        const float gi = fsigm(S0 + p1v.x + b1v.x);                            \
        const float gf = fsigm(S1 + p1v.y + b1v.y);                            \
        const float gg = ftanh(S2 + p1v.z + b1v.z);                            \
        const float go = fsigm(S3 + p1v.w + b1v.w);                            \
        cst = fmaf(gf, cst, gi * gg);                                          \
        if (q2 == 0) hb[WB][1][uu] = go * ftanh(cst);                          \
      }                                                                        \
    }                                                                          \
    cur = nxt;                                                                 \
    __syncthreads();                                                           \
  } while (0)

  for (int tt = 0; tt < SEQ + 2; tt += 2) {   // TT = 0..513
#pragma unroll
    for (int j = 0; j < 4; ++j) {
      pin4(w[j][0]); pin4(w[j][1]); pin4(w[j][2]); pin4(w[j][3]);
    }
    LSTM_STEP(tt, 0, 1);
    LSTM_STEP(tt + 1, 1, 0);
  }
#undef LSTM_STEP
  // grp2's last write (TT=513, WB=0): hb[0][1][*] = h1[SEQ-1] = xl_out.

  // ---------------- fused heads: c = [h1(64) | xg_b(1024)] ----------------
  if (t < 64) cbuf[t] = hb[0][1][t];
  for (int k = t; k < 1024; k += 768) cbuf[64 + k] = xg[b * 1024 + k];
  __syncthreads();
  if (t < 96) {
    const int head = t >> 5, h = t & 31;
    const float* w1 = (head == 0) ? dw1 : (head == 1) ? rw1 : vw1;
    const float* b1 = (head == 0) ? db1 : (head == 1) ? rb1 : vb1;
    float a0 = 0.f, a1v = 0.f, a2v = 0.f, a3v = 0.f;
    for (int k = 0; k < 1088; k += 4) {
      a0  = fmaf(cbuf[k],     w1[k * 32 + h],       a0);
      a1v = fmaf(cbuf[k + 1], w1[(k + 1) * 32 + h], a1v);
      a2v = fmaf(cbuf[k + 2], w1[(k + 2) * 32 + h], a2v);
      a3v = fmaf(cbuf[k + 3], w1[(k + 3) * 32 + h], a3v);
    }
    hidc[head * 32 + h] = fmaxf(b1[h] + ((a0 + a1v) + (a2v + a3v)), 0.f);
  }
  __syncthreads();
  if (t < 4) {
    const int head2 = (t < 2) ? t : 2;
    const int o = (t < 2) ? 0 : (t - 2);
    const int odim = (t < 2) ? 1 : 2;
    const float* w2  = (head2 == 0) ? dw2 : (head2 == 1) ? rw2 : vw2;
    const float* b2p = (head2 == 0) ? db2 : (head2 == 1) ? rb2 : vb2;
    float acc = b2p[o];
    for (int hh = 0; hh < 32; ++hh)
      acc = fmaf(hidc[head2 * 32 + hh], w2[hh * odim + o], acc);
    const int off = (t == 0) ? b : (t == 1) ? (4 + b) : (8 + 2 * b + o);
    out[off] = acc;   // [dir(4) | ret(4) | vol(4x2)] flat
  }
}

// ---------------------------------------------------------------------------
extern "C" void kernel_launch(void* const* d_in, const int* in_sizes, int n_in,
                              void* d_out, int out_size, void* d_ws, size_t ws_size,
                              hipStream_t stream) {
  const float* x     = (const float*)d_in[0];
  const int*   adj   = (const int*)  d_in[1];
  const float* emb_w = (const float*)d_in[2];
  const float* emb_b = (const float*)d_in[3];
  const float* g1W   = (const float*)d_in[4];
  const float* g1a   = (const float*)d_in[5];
  const float* g2W   = (const float*)d_in[6];
  const float* g2a   = (const float*)d_in[7];
  const float* Wih0  = (const float*)d_in[8];
  const float* Whh0  = (const float*)d_in[9];
  const float* bih0  = (const float*)d_in[10];
  const float* bhh0  = (const float*)d_in[11];
  const float* Wih1  = (const float*)d_in[12];
  const float* Whh1  = (const float*)d_in[13];
  const float* bih1  = (const float*)d_in[14];
  const float* bhh1  = (const float*)d_in[15];
  const float* dw1 = (const float*)d_in[16]; const float* db1 = (const float*)d_in[17];
  const float* dw2 = (const float*)d_in[18]; const float* db2 = (const float*)d_in[19];
  const float* rw1 = (const float*)d_in[20]; const float* rb1 = (const float*)d_in[21];
  const float* rw2 = (const float*)d_in[22]; const float* rb2 = (const float*)d_in[23];
  const float* vw1 = (const float*)d_in[24]; const float* vb1 = (const float*)d_in[25];
  const float* vw2 = (const float*)d_in[26]; const float* vb2 = (const float*)d_in[27];

  float* ws = (float*)d_ws;
  float* X0 = ws;                         // SEQ*BATCH*256 floats = 2 MB (transposed)
  float* xg = ws + SEQ * BATCH * G4;      // 4096 floats
  float* out = (float*)d_out;

  hipLaunchKernelGGL(prep_kernel, dim3(132), dim3(512), 0, stream,
                     x, Wih0, bih0, bhh0, X0,
                     adj, emb_w, emb_b, g1W, g1a, g2W, g2a, xg);
  hipLaunchKernelGGL(lstm_heads, dim3(BATCH), dim3(768), 0, stream,
                     X0, Whh0, Wih1, Whh1, bih1, bhh1, xg,
                     dw1, db1, dw2, db2, rw1, rb1, rw2, rb2,
                     vw1, vb1, vw2, vb2, out);
}